// Round 1
// baseline (536.971 us; speedup 1.0000x reference)
//
#include <hip/hip_runtime.h>

// TankModel: B independent rows, each a sequential 4-tank scan over T steps.
// One thread per row; loop runs only to lengths[b] (mask==1 region), tail is
// zero-filled (reference output is exactly 0 for t >= len). Constants folded:
//   max(r*(w - h + p), 0) == max(fmaf(r, (w+p), -r*h), 0)
// 16-step prefetch blocks hide HBM latency (only 128 waves in flight).

__global__ __launch_bounds__(64)
void tank_kernel(
    const float* __restrict__ P,
    const int*   __restrict__ lengths,
    const float* __restrict__ S0,
    const float* __restrict__ AreaP,
    const float* __restrict__ p_r1h1, const float* __restrict__ p_r1h2,
    const float* __restrict__ p_h1h1, const float* __restrict__ p_h1h2,
    const float* __restrict__ p_ri2,  const float* __restrict__ p_ro2,
    const float* __restrict__ p_h2,
    const float* __restrict__ p_ri3,  const float* __restrict__ p_ro3,
    const float* __restrict__ p_h3,
    const float* __restrict__ p_ri4,  const float* __restrict__ p_ro4,
    float* __restrict__ Out,
    int B, int T)
{
    const int b = blockIdx.x * 64 + threadIdx.x;
    if (b >= B) return;

    // Uniform scalar parameters (same for every lane; one-time loads).
    const float r1h1 = p_r1h1[0], r1h2 = p_r1h2[0];
    const float k1 = -r1h1 * p_h1h1[0];
    const float k2 = -r1h2 * p_h1h2[0];
    const float ri2 = p_ri2[0];
    const float ro2 = p_ro2[0];
    const float k3 = -ro2 * p_h2[0];
    const float ri3 = p_ri3[0];
    const float ro3 = p_ro3[0];
    const float k4 = -ro3 * p_h3[0];
    const float ri4 = p_ri4[0];
    const float ro4 = p_ro4[0];
    const float scale = AreaP[0] * (1.0f / 3.6f);

    float w1 = S0[0], w2 = S0[1], w3 = S0[2], w4 = S0[3];

    int len = lengths[b];
    if (len > T) len = T;
    if (len < 0) len = 0;

    const int TC = T >> 2;  // float4 chunks per row (T % 4 == 0)
    const float4* __restrict__ Pv = reinterpret_cast<const float4*>(P)   + (size_t)b * TC;
    float4*       __restrict__ Ov = reinterpret_cast<float4*>(Out)       + (size_t)b * TC;

#define STEP(pp, oo) do {                                   \
        float t1 = w1 + (pp);                               \
        float a1 = fmaxf(fmaf(r1h1, t1, k1), 0.0f);         \
        float a2 = fmaxf(fmaf(r1h2, t1, k2), 0.0f);         \
        float o12 = fmaxf(ri2 * t1, 0.0f);                  \
        float of1 = a1 + a2;                                \
        w1 = t1 - of1 - o12;                                \
        float t2 = w2 + o12;                                \
        float of2 = fmaxf(fmaf(ro2, t2, k3), 0.0f);         \
        float o23 = fmaxf(ri3 * t2, 0.0f);                  \
        w2 = t2 - of2 - o23;                                \
        float t3 = w3 + o23;                                \
        float of3 = fmaxf(fmaf(ro3, t3, k4), 0.0f);         \
        float o34 = fmaxf(ri4 * t3, 0.0f);                  \
        w3 = t3 - of3 - o34;                                \
        float t4v = w4 + o34;                               \
        float of4 = fmaxf(ro4 * t4v, 0.0f);                 \
        w4 = t4v - of4;                                     \
        (oo) = ((of1 + of2) + (of3 + of4)) * scale;         \
    } while (0)

    const int nfull = len >> 2;   // full 4-step chunks in the valid region
    const int nblk  = nfull >> 2; // 16-step prefetch blocks

    float4 f0, f1, f2, f3;
    if (nblk > 0) { f0 = Pv[0]; f1 = Pv[1]; f2 = Pv[2]; f3 = Pv[3]; }

    int t4 = 0;
    for (int blk = 0; blk < nblk; ++blk) {
        float4 u0 = f0, u1 = f1, u2 = f2, u3 = f3;
        // Prefetch next block (clamped in-row; harmless over-read for the
        // last block of short lanes — never consumed).
        int nb = (blk + 1) << 2;
        int nbi = (nb + 4 <= TC) ? nb : (TC - 4);
        f0 = Pv[nbi]; f1 = Pv[nbi + 1]; f2 = Pv[nbi + 2]; f3 = Pv[nbi + 3];

        float4 o;
        STEP(u0.x, o.x); STEP(u0.y, o.y); STEP(u0.z, o.z); STEP(u0.w, o.w);
        Ov[t4 + 0] = o;
        STEP(u1.x, o.x); STEP(u1.y, o.y); STEP(u1.z, o.z); STEP(u1.w, o.w);
        Ov[t4 + 1] = o;
        STEP(u2.x, o.x); STEP(u2.y, o.y); STEP(u2.z, o.z); STEP(u2.w, o.w);
        Ov[t4 + 2] = o;
        STEP(u3.x, o.x); STEP(u3.y, o.y); STEP(u3.z, o.z); STEP(u3.w, o.w);
        Ov[t4 + 3] = o;
        t4 += 4;
    }

    // Leftover full chunks (< 4 of them)
    for (; t4 < nfull; ++t4) {
        float4 p4 = Pv[t4];
        float4 o;
        STEP(p4.x, o.x); STEP(p4.y, o.y); STEP(p4.z, o.z); STEP(p4.w, o.w);
        Ov[t4] = o;
    }

    // Boundary partial chunk (len % 4 != 0)
    int t = t4 << 2;
    if (t < len) {
        float4 p4 = Pv[t4];
        float4 o = make_float4(0.0f, 0.0f, 0.0f, 0.0f);
        if (t + 0 < len) STEP(p4.x, o.x);
        if (t + 1 < len) STEP(p4.y, o.y);
        if (t + 2 < len) STEP(p4.z, o.z);
        if (t + 3 < len) STEP(p4.w, o.w);
        Ov[t4] = o;
        ++t4;
    }

    // Zero-fill the masked tail (reference outputs exactly 0 there; d_out is
    // poisoned before every launch so we must write it).
    const float4 z = make_float4(0.0f, 0.0f, 0.0f, 0.0f);
    for (; t4 < TC; ++t4) Ov[t4] = z;

#undef STEP
}

extern "C" void kernel_launch(void* const* d_in, const int* in_sizes, int n_in,
                              void* d_out, int out_size, void* d_ws, size_t ws_size,
                              hipStream_t stream) {
    const float* P        = (const float*)d_in[0];
    const int*   lengths  = (const int*)d_in[1];
    const float* S0       = (const float*)d_in[2];
    const float* Area     = (const float*)d_in[3];
    // d_in[4] = baseflow (unused by forward)
    const float* r1h1 = (const float*)d_in[5];
    const float* r1h2 = (const float*)d_in[6];
    const float* h1h1 = (const float*)d_in[7];
    const float* h1h2 = (const float*)d_in[8];
    const float* ri2  = (const float*)d_in[9];
    const float* ro2  = (const float*)d_in[10];
    const float* h2   = (const float*)d_in[11];
    const float* ri3  = (const float*)d_in[12];
    const float* ro3  = (const float*)d_in[13];
    const float* h3   = (const float*)d_in[14];
    const float* ri4  = (const float*)d_in[15];
    const float* ro4  = (const float*)d_in[16];
    float* out = (float*)d_out;

    const int B = in_sizes[1];
    const int T = in_sizes[0] / B;

    dim3 block(64);
    dim3 grid((B + 63) / 64);
    hipLaunchKernelGGL(tank_kernel, grid, block, 0, stream,
                       P, lengths, S0, Area,
                       r1h1, r1h2, h1h1, h1h2,
                       ri2, ro2, h2, ri3, ro3, h3, ri4, ro4,
                       out, B, T);
}